// Round 11
// baseline (561.538 us; speedup 1.0000x reference)
//
#include <hip/hip_runtime.h>

#define T_TOK 12000
#define NSLOT 24000
#define DIN 2560
#define DH 512
#define DOUT 2048
#define NEXP 8
#define MSH 12000
#define SHBASE 24000   // row offset of shared region in ACT/O16 buffers

typedef unsigned short u16;
typedef unsigned int u32;
typedef __attribute__((ext_vector_type(4))) float f32x4;
typedef __attribute__((ext_vector_type(8))) short short8;
typedef __attribute__((ext_vector_type(4))) u16 u16x4;
typedef __attribute__((ext_vector_type(8))) u16 u16x8;

__device__ __forceinline__ u16 f2bf(float f) {
  u32 u = __builtin_bit_cast(u32, f);
  return (u16)((u + 0x7fffu + ((u >> 16) & 1u)) >> 16);
}
__device__ __forceinline__ float bf2f(u16 h) {
  return __builtin_bit_cast(float, (u32)h << 16);
}

__device__ __forceinline__ void gload_lds16(const void* g, void* l) {
  __builtin_amdgcn_global_load_lds((const __attribute__((address_space(1))) u32*)g,
                                   (__attribute__((address_space(3))) u32*)l, 16, 0, 0);
}

// ---------------- merged weight f32 -> bf16 (one launch) ----------------
#define CN0 655360           // 1024*2560/4
#define CN1 262144           // 2048*512/4
#define CN2 5242880          // 8*1024*2560/4
#define CN3 2097152          // 8*2048*512/4
__global__ __launch_bounds__(256) void cvt4_kernel(
    const float* __restrict__ s0, u16* __restrict__ d0,
    const float* __restrict__ s1, u16* __restrict__ d1,
    const float* __restrict__ s2, u16* __restrict__ d2,
    const float* __restrict__ s3, u16* __restrict__ d3) {
  int i = blockIdx.x * 256 + threadIdx.x;
  const float* s; u16* d;
  if (i < CN0) { s = s0; d = d0; }
  else if (i < CN0 + CN1) { i -= CN0; s = s1; d = d1; }
  else if (i < CN0 + CN1 + CN2) { i -= CN0 + CN1; s = s2; d = d2; }
  else { i -= CN0 + CN1 + CN2; if (i >= CN3) return; s = s3; d = d3; }
  f32x4 v = ((const f32x4*)s)[i];
  u16x4 o = { f2bf(v.x), f2bf(v.y), f2bf(v.z), f2bf(v.w) };
  ((u16x4*)d)[i] = o;
}

// ---------------- fused pre-LN + router: one wave/token, rw via LDS --------
__global__ __launch_bounds__(256) void ln_router_kernel(
    const float* __restrict__ x, const float* __restrict__ gamma, const float* __restrict__ beta,
    const float* __restrict__ rw, const float* __restrict__ rb,
    u16* __restrict__ nx, int* __restrict__ tok_e, float* __restrict__ tok_w,
    int* __restrict__ count) {
  const int tid = threadIdx.x;
  const int t = blockIdx.x * 4 + (tid >> 6);
  const int lane = tid & 63;
  const f32x4* xrow = (const f32x4*)(x + (size_t)t * DIN);

  __shared__ float rwl[NEXP][256];   // 8 KB chunk of router weights

  f32x4 xv[10];
  float s = 0.f, s2 = 0.f;
#pragma unroll
  for (int c = 0; c < 10; ++c) {
    xv[c] = xrow[c * 64 + lane];
#pragma unroll
    for (int i = 0; i < 4; ++i) { s += xv[c][i]; s2 += xv[c][i] * xv[c][i]; }
  }
#pragma unroll
  for (int off = 32; off > 0; off >>= 1) {
    s += __shfl_xor(s, off);
    s2 += __shfl_xor(s2, off);
  }
  const float mean = s * (1.0f / DIN);
  const float var = s2 * (1.0f / DIN) - mean * mean;
  const float rstd = rsqrtf(var + 1e-6f);

  u16* nxrow = nx + (size_t)t * DIN;
#pragma unroll
  for (int c = 0; c < 10; ++c) {
    f32x4 g = ((const f32x4*)gamma)[c * 64 + lane];
    f32x4 b = ((const f32x4*)beta)[c * 64 + lane];
    xv[c] = (xv[c] - mean) * rstd * g + b;
    u16x4 p = { f2bf(xv[c].x), f2bf(xv[c].y), f2bf(xv[c].z), f2bf(xv[c].w) };
    ((u16x4*)nxrow)[c * 64 + lane] = p;
  }

  float lp[NEXP];
#pragma unroll
  for (int e = 0; e < NEXP; ++e) lp[e] = 0.f;
#pragma unroll
  for (int c = 0; c < 10; ++c) {
    __syncthreads();
#pragma unroll
    for (int e = 0; e < NEXP; ++e) rwl[e][tid] = rw[(size_t)e * DIN + c * 256 + tid];
    __syncthreads();
#pragma unroll
    for (int e = 0; e < NEXP; ++e) {
      f32x4 r = *(const f32x4*)&rwl[e][lane * 4];
      lp[e] += xv[c].x * r.x + xv[c].y * r.y + xv[c].z * r.z + xv[c].w * r.w;
    }
  }
#pragma unroll
  for (int e = 0; e < NEXP; ++e)
#pragma unroll
    for (int off = 32; off > 0; off >>= 1) lp[e] += __shfl_xor(lp[e], off);

  if (lane == 0) {
    float lg[NEXP];
#pragma unroll
    for (int e = 0; e < NEXP; ++e) lg[e] = lp[e] + rb[e];
    float mx = lg[0];
#pragma unroll
    for (int e = 1; e < NEXP; ++e) mx = fmaxf(mx, lg[e]);
    float p[NEXP], ps = 0.f;
#pragma unroll
    for (int e = 0; e < NEXP; ++e) { p[e] = expf(lg[e] - mx); ps += p[e]; }
    int i0 = 0;
#pragma unroll
    for (int e = 1; e < NEXP; ++e) if (p[e] > p[i0]) i0 = e;
    int i1 = (i0 == 0) ? 1 : 0;
#pragma unroll
    for (int e = 0; e < NEXP; ++e) if (e != i0 && p[e] > p[i1]) i1 = e;
    float w0 = p[i0] / ps, w1 = p[i1] / ps;
    const float inv = 1.0f / (w0 + w1 + 1e-20f);
    w0 *= inv; w1 *= inv;
    tok_e[2 * t] = i0; tok_e[2 * t + 1] = i1;
    tok_w[2 * t] = w0; tok_w[2 * t + 1] = w1;
    atomicAdd(&count[i0 * 32], 1);
    atomicAdd(&count[i1 * 32], 1);
  }
}

__global__ void prefix_kernel(const int* __restrict__ count, int* __restrict__ prefix) {
  if (threadIdx.x == 0) {
    int acc = 0;
    for (int e = 0; e < NEXP; ++e) { prefix[e] = acc; acc += count[e * 32]; }
  }
}

__global__ __launch_bounds__(256) void assign_kernel(
    const int* __restrict__ tok_e, const float* __restrict__ tok_w, const int* __restrict__ prefix,
    int* __restrict__ cursor, int* __restrict__ slot_token, float* __restrict__ slot_w,
    int* __restrict__ token_slot) {
  const int t = blockIdx.x * 256 + threadIdx.x;
  if (t >= T_TOK) return;
#pragma unroll
  for (int k = 0; k < 2; ++k) {
    const int e = tok_e[2 * t + k];
    const int pos = atomicAdd(&cursor[e * 32], 1);
    const int sl = prefix[e] + pos;
    slot_token[sl] = t;
    slot_w[sl] = tok_w[2 * t + k];
    token_slot[2 * t + k] = sl;
  }
}

// ---------------- FFN1 fused with SwiGLU (FROZEN from R10) ------------------
__global__ __launch_bounds__(256, 2) void gemm_ffn1(
    const u16* __restrict__ A0, const u16* __restrict__ Bsh, const u16* __restrict__ Bex,
    u16* __restrict__ ACT,
    const int* __restrict__ cnt32, const int* __restrict__ prefix,
    const int* __restrict__ slot_token) {
  constexpr int K = 2560;
  constexpr int NX = 8;            // 512 act cols / 64
  __shared__ u16 ldsA[128 * 64];
  __shared__ u16 ldsG[64 * 64];
  __shared__ u16 ldsV[64 * 64];

  int A_act = 0;
#pragma unroll
  for (int ee = 0; ee < 9; ++ee) {
    const int c = (ee == 8) ? MSH : cnt32[ee * 32];
    A_act += ((c + 127) >> 7) * NX;
  }
  const int bid = blockIdx.x;
  if (bid >= A_act) return;

  const int xcd = bid & 7, rank = bid >> 3;
  const int q = A_act >> 3, r = A_act & 7;
  const int tile = (xcd < r ? xcd * (q + 1) : r * (q + 1) + (xcd - r) * q) + rank;

  int e = 8, local = 0, m_valid = MSH, row_off = 0;
  {
    int bacc = 0, found = 0;
#pragma unroll
    for (int ee = 0; ee < 9; ++ee) {
      const int c = (ee == 8) ? MSH : cnt32[ee * 32];
      const int w = ((c + 127) >> 7) * NX;
      if (!found && tile < bacc + w) {
        found = 1; e = ee; local = tile - bacc; m_valid = c;
        row_off = (ee == 8) ? 0 : prefix[ee];
      }
      bacc += w;
    }
  }
  const int ty = local / NX;
  const int tx = local % NX;
  const int crow_base = (e == 8) ? SHBASE : row_off;
  const u16* Bb = (e == 8) ? Bsh : Bex + (size_t)e * 1024 * K;

  const int tid = threadIdx.x;
  const int lane = tid & 63;
  const int wid = tid >> 6;
  const int sk8 = ((lane & 7) ^ (lane >> 3)) * 8;   // pre-swizzled 16B slot

  const u16* aptr[4];
#pragma unroll
  for (int i = 0; i < 4; ++i) {
    const int rr = wid * 32 + i * 8 + (lane >> 3);
    int gr = ty * 128 + rr;
    gr = gr < m_valid ? gr : (m_valid - 1);
    const int ar = (e == 8) ? gr : slot_token[row_off + gr];
    aptr[i] = A0 + (size_t)ar * K;
  }
  const u16* gptr[2];
  const u16* vptr[2];
#pragma unroll
  for (int j = 0; j < 2; ++j) {
    const int rr = wid * 16 + j * 8 + (lane >> 3);
    gptr[j] = Bb + (size_t)(tx * 64 + rr) * K;
    vptr[j] = Bb + (size_t)(512 + tx * 64 + rr) * K;
  }

  const f32x4 zero = {0.f, 0.f, 0.f, 0.f};
  f32x4 accg[4][2], accv[4][2];
#pragma unroll
  for (int m = 0; m < 4; ++m)
#pragma unroll
    for (int n = 0; n < 2; ++n) { accg[m][n] = zero; accv[m][n] = zero; }

  const int wr = (wid >> 1) * 64;   // row half
  const int wc = (wid & 1) * 32;    // act-col half
  const int fr = lane & 15;
  const int fk = (lane >> 4) * 8;

  for (int k0 = 0; k0 < K; k0 += 64) {
#pragma unroll
    for (int i = 0; i < 4; ++i)
      gload_lds16(aptr[i] + k0 + sk8, &ldsA[(wid * 4 + i) * 512]);
#pragma unroll
    for (int j = 0; j < 2; ++j) {
      gload_lds16(gptr[j] + k0 + sk8, &ldsG[(wid * 2 + j) * 512]);
      gload_lds16(vptr[j] + k0 + sk8, &ldsV[(wid * 2 + j) * 512]);
    }
    __syncthreads();
#pragma unroll
    for (int kk = 0; kk < 2; ++kk) {
      short8 af[4], bg[2], bv[2];
      const int kbs = (kk * 32 + fk) ^ ((lane & 7) << 3);
#pragma unroll
      for (int m = 0; m < 4; ++m)
        af[m] = *(const short8*)&ldsA[(wr + m * 16 + fr) * 64 + kbs];
#pragma unroll
      for (int n = 0; n < 2; ++n) {
        bg[n] = *(const short8*)&ldsG[(wc + n * 16 + fr) * 64 + kbs];
        bv[n] = *(const short8*)&ldsV[(wc + n * 16 + fr) * 64 + kbs];
      }
#pragma unroll
      for (int m = 0; m < 4; ++m)
#pragma unroll
        for (int n = 0; n < 2; ++n) {
          accg[m][n] = __builtin_amdgcn_mfma_f32_16x16x32_bf16(af[m], bg[n], accg[m][n], 0, 0, 0);
          accv[m][n] = __builtin_amdgcn_mfma_f32_16x16x32_bf16(af[m], bv[n], accv[m][n], 0, 0, 0);
        }
    }
    __syncthreads();
  }

  const int ccol = tx * 64 + wc + (lane & 15);
#pragma unroll
  for (int m = 0; m < 4; ++m) {
#pragma unroll
    for (int i = 0; i < 4; ++i) {
      const int row = wr + m * 16 + (lane >> 4) * 4 + i;
      const int gr = ty * 128 + row;
      if (gr < m_valid) {
        u16* crow = ACT + (size_t)(crow_base + gr) * DH;
#pragma unroll
        for (int n = 0; n < 2; ++n) {
          const float g = accg[m][n][i];
          const float v = accv[m][n][i];
          const float sig = 1.0f / (1.0f + __expf(-g));
          crow[ccol + n * 16] = f2bf(g * sig * v);
        }
      }
    }
  }
}

// ---------------- FFN2: BK=128 + LDS-transpose coalesced epilogue -----------
// K=512 -> 4 K-iterations (halves barrier-drain count vs BK=64). LDS 64 KB
// (A|B 32 KB each), 2 blocks/CU unchanged (bounds(256,2)). Swizzle for the
// 256B-row-stride tile: stage slot (lane&15)^(row&15) on the GLOBAL source,
// read slot (kk*4+(lane>>4))^fr -- involution, residual 2-way (free).
// Accumulation order over K identical to BK=64 (ascending) -> bit-identical.
// Epilogue: acc -> bf16 into padded LDS [128][144] (288B stride, conflict-
// free), then 8 coalesced u16x8 stores/thread (was 64 scattered u16 stores).
__global__ __launch_bounds__(256, 2) void gemm_ffn2(
    const u16* __restrict__ A0, const u16* __restrict__ Bsh, const u16* __restrict__ Bex,
    u16* __restrict__ C,
    const int* __restrict__ cnt32, const int* __restrict__ prefix,
    const float* __restrict__ slot_w) {
  constexpr int N = 2048;
  constexpr int K = 512;
  constexpr int NX = 16;
  __shared__ u16 ldsbuf[2 * 128 * 128];   // A | B ; epilogue reuses as T[128][144]

  int A_act = 0;
#pragma unroll
  for (int ee = 0; ee < 9; ++ee) {
    const int c = (ee == 8) ? MSH : cnt32[ee * 32];
    A_act += ((c + 127) >> 7) * NX;
  }
  const int bid = blockIdx.x;
  if (bid >= A_act) return;

  const int xcd = bid & 7, rank = bid >> 3;
  const int q = A_act >> 3, r = A_act & 7;
  const int tile = (xcd < r ? xcd * (q + 1) : r * (q + 1) + (xcd - r) * q) + rank;

  int e = 8, local = 0, m_valid = MSH, row_off = 0;
  {
    int bacc = 0, found = 0;
#pragma unroll
    for (int ee = 0; ee < 9; ++ee) {
      const int c = (ee == 8) ? MSH : cnt32[ee * 32];
      const int w = ((c + 127) >> 7) * NX;
      if (!found && tile < bacc + w) {
        found = 1; e = ee; local = tile - bacc; m_valid = c;
        row_off = (ee == 8) ? 0 : prefix[ee];
      }
      bacc += w;
    }
  }
  const int ty = local / NX;
  const int tx = local % NX;
  const int crow_base = (e == 8) ? SHBASE : row_off;
  const u16* Bb = (e == 8) ? Bsh : Bex + (size_t)e * N * K;

  const int tid = threadIdx.x;
  const int lane = tid & 63;
  const int wid = tid >> 6;

  // staging: 8 instrs each for A and B; instr i covers 4 rows, this thread's
  // row rr and pre-swizzled 16B slot (lane&15)^(rr&15).
  const u16* aptr[8];
  const u16* bptr[8];
#pragma unroll
  for (int i = 0; i < 8; ++i) {
    const int rr = (wid * 8 + i) * 4 + (lane >> 4);
    const int sg = ((lane & 15) ^ (rr & 15)) * 8;
    int gr = ty * 128 + rr;
    gr = gr < m_valid ? gr : (m_valid - 1);
    aptr[i] = A0 + (size_t)(crow_base + gr) * K + sg;
    bptr[i] = Bb + (size_t)(tx * 128 + rr) * K + sg;
  }

  const f32x4 zero = {0.f, 0.f, 0.f, 0.f};
  f32x4 acc[4][4];
#pragma unroll
  for (int m = 0; m < 4; ++m)
#pragma unroll
    for (int n = 0; n < 4; ++n) acc[m][n] = zero;

  const int wr = (wid >> 1) * 64;
  const int wc = (wid & 1) * 64;
  const int fr = lane & 15;

  for (int k0 = 0; k0 < K; k0 += 128) {
#pragma unroll
    for (int i = 0; i < 8; ++i) {
      gload_lds16(aptr[i] + k0, &ldsbuf[(wid * 8 + i) * 512]);
      gload_lds16(bptr[i] + k0, &ldsbuf[16384 + (wid * 8 + i) * 512]);
    }
    __syncthreads();
#pragma unroll
    for (int kk = 0; kk < 4; ++kk) {
      short8 af[4], bfm[4];
      const int so = ((kk * 4 + (lane >> 4)) ^ fr) * 8;   // swizzled u16 offset
#pragma unroll
      for (int m = 0; m < 4; ++m)
        af[m] = *(const short8*)&ldsbuf[(wr + m * 16 + fr) * 128 + so];
#pragma unroll
      for (int n = 0; n < 4; ++n)
        bfm[n] = *(const short8*)&ldsbuf[16384 + (wc + n * 16 + fr) * 128 + so];
#pragma unroll
      for (int m = 0; m < 4; ++m)
#pragma unroll
        for (int n = 0; n < 4; ++n)
          acc[m][n] = __builtin_amdgcn_mfma_f32_16x16x32_bf16(af[m], bfm[n], acc[m][n], 0, 0, 0);
    }
    __syncthreads();
  }

  // ---- epilogue: scale, pack bf16 into padded LDS, coalesced stores ----
  u16* ldsT = ldsbuf;   // [128][144] u16, 288B row stride (conflict-free)
#pragma unroll
  for (int m = 0; m < 4; ++m) {
#pragma unroll
    for (int i = 0; i < 4; ++i) {
      const int row = wr + m * 16 + (lane >> 4) * 4 + i;
      int gr = ty * 128 + row;
      gr = gr < m_valid ? gr : (m_valid - 1);
      const float wscale = (e == 8) ? 1.0f : slot_w[row_off + gr];
#pragma unroll
      for (int n = 0; n < 4; ++n)
        ldsT[row * 144 + wc + n * 16 + (lane & 15)] = f2bf(acc[m][n][i] * wscale);
    }
  }
  __syncthreads();
  {
    const int row = tid >> 1;
    const int ch = (tid & 1) * 64;
    const int gr = ty * 128 + row;
    if (gr < m_valid) {
      u16* crow = C + (size_t)(crow_base + gr) * N + tx * 128 + ch;
#pragma unroll
      for (int j = 0; j < 8; ++j)
        *(u16x8*)&crow[j * 8] = *(const u16x8*)&ldsT[row * 144 + ch + j * 8];
    }
  }
}

// ---------------- final LN: one wave per token ------------------------------
__global__ __launch_bounds__(256) void final_ln_kernel(
    const u16* __restrict__ O16, const int* __restrict__ token_slot,
    const float* __restrict__ gamma, const float* __restrict__ beta, float* __restrict__ out) {
  const int t = blockIdx.x * 4 + (threadIdx.x >> 6);
  const int lane = threadIdx.x & 63;
  const int s0 = token_slot[2 * t], s1 = token_slot[2 * t + 1];
  const u16* rsh = O16 + (size_t)(SHBASE + t) * DOUT;
  const u16* r0 = O16 + (size_t)s0 * DOUT;
  const u16* r1 = O16 + (size_t)s1 * DOUT;

  float v[32];
  float s = 0.f, s2 = 0.f;
#pragma unroll
  for (int c = 0; c < 4; ++c) {
    const int col = c * 512 + lane * 8;
    u16x8 a8 = *(const u16x8*)&rsh[col];
    u16x8 b8 = *(const u16x8*)&r0[col];
    u16x8 c8 = *(const u16x8*)&r1[col];
#pragma unroll
    for (int i = 0; i < 8; ++i) {
      const float x = bf2f(a8[i]) + bf2f(b8[i]) + bf2f(c8[i]);
      v[c * 8 + i] = x;
      s += x;
      s2 += x * x;
    }
  }
#pragma unroll
  for (int off = 32; off > 0; off >>= 1) {
    s += __shfl_xor(s, off);
    s2 += __shfl_xor(s2, off);
  }
  const float mean = s * (1.0f / DOUT);
  const float var = s2 * (1.0f / DOUT) - mean * mean;
  const float rstd = rsqrtf(var + 1e-6f);

  float* orow = out + (size_t)t * DOUT;
#pragma unroll
  for (int c = 0; c < 4; ++c) {
    const int col = c * 512 + lane * 8;
    f32x4 g0 = ((const f32x4*)gamma)[col >> 2], g1 = ((const f32x4*)gamma)[(col >> 2) + 1];
    f32x4 b0 = ((const f32x4*)beta)[col >> 2],  b1 = ((const f32x4*)beta)[(col >> 2) + 1];
    f32x4 o0, o1;
#pragma unroll
    for (int i = 0; i < 4; ++i) {
      o0[i] = (v[c * 8 + i] - mean) * rstd * g0[i] + b0[i];
      o1[i] = (v[c * 8 + 4 + i] - mean) * rstd * g1[i] + b1[i];
    }
    *(f32x4*)&orow[col] = o0;
    *(f32x4*)&orow[col + 4] = o1;
  }
}

extern "C" void kernel_launch(void* const* d_in, const int* in_sizes, int n_in,
                              void* d_out, int out_size, void* d_ws, size_t ws_size,
                              hipStream_t stream) {
  (void)in_sizes; (void)n_in; (void)out_size; (void)ws_size;
  const float* x = (const float*)d_in[0];
  const float* ln_pre_g = (const float*)d_in[1];
  const float* ln_pre_b = (const float*)d_in[2];
  const float* router_w = (const float*)d_in[3];
  const float* router_b = (const float*)d_in[4];
  const float* shared_w12 = (const float*)d_in[5];
  const float* shared_w3 = (const float*)d_in[6];
  const float* experts_w12 = (const float*)d_in[7];
  const float* experts_w3 = (const float*)d_in[8];
  const float* ln_post_g = (const float*)d_in[9];
  const float* ln_post_b = (const float*)d_in[10];
  float* out = (float*)d_out;

  size_t off = 0;
  char* ws = (char*)d_ws;
  auto take = [&](size_t bytes) -> void* {
    void* p = ws + off;
    off += (bytes + 255) & ~(size_t)255;
    return p;
  };
  u16* w12s = (u16*)take((size_t)1024 * 2560 * 2);
  u16* w3s  = (u16*)take((size_t)2048 * 512 * 2);
  u16* ew12 = (u16*)take((size_t)NEXP * 1024 * 2560 * 2);
  u16* ew3  = (u16*)take((size_t)NEXP * 2048 * 512 * 2);
  u16* nx   = (u16*)take((size_t)T_TOK * DIN * 2);
  u16* act  = (u16*)take((size_t)36000 * DH * 2);
  u16* O16  = (u16*)take((size_t)36000 * DOUT * 2);
  int* tok_e = (int*)take(NSLOT * 4);
  float* tok_w = (float*)take(NSLOT * 4);
  int* slot_token = (int*)take(NSLOT * 4);
  float* slot_w = (float*)take(NSLOT * 4);
  int* token_slot = (int*)take(NSLOT * 4);
  int* cnt = (int*)take(3 * 8 * 32 * 4);   // count[8*32] | cursor[8*32] | prefix[8]
  int* cursor = cnt + 8 * 32;
  int* prefix = cnt + 2 * 8 * 32;

  hipMemsetAsync(cnt, 0, 3 * 8 * 32 * 4, stream);

  cvt4_kernel<<<(CN0 + CN1 + CN2 + CN3) / 256, 256, 0, stream>>>(
      shared_w12, w12s, shared_w3, w3s, experts_w12, ew12, experts_w3, ew3);

  ln_router_kernel<<<T_TOK / 4, 256, 0, stream>>>(x, ln_pre_g, ln_pre_b, router_w, router_b,
                                                  nx, tok_e, tok_w, cnt);
  prefix_kernel<<<1, 64, 0, stream>>>(cnt, prefix);
  assign_kernel<<<(T_TOK + 255) / 256, 256, 0, stream>>>(tok_e, tok_w, prefix, cursor,
                                                         slot_token, slot_w, token_slot);

  // y-tiles (128-row): experts <= 195, shared 94 -> 289 max
  gemm_ffn1<<<289 * 8, 256, 0, stream>>>(nx, w12s, ew12, act, cnt, prefix, slot_token);
  gemm_ffn2<<<289 * 16, 256, 0, stream>>>(act, w3s, ew3, O16, cnt, prefix, slot_w);

  final_ln_kernel<<<T_TOK / 4, 256, 0, stream>>>(O16, token_slot, ln_post_g, ln_post_b, out);
}

// Round 12
// 533.725 us; speedup vs baseline: 1.0521x; 1.0521x over previous
//
#include <hip/hip_runtime.h>

#define T_TOK 12000
#define NSLOT 24000
#define DIN 2560
#define DH 512
#define DOUT 2048
#define NEXP 8
#define MSH 12000
#define SHBASE 24000   // row offset of shared region in ACT/O16 buffers

typedef unsigned short u16;
typedef unsigned int u32;
typedef __attribute__((ext_vector_type(4))) float f32x4;
typedef __attribute__((ext_vector_type(8))) short short8;
typedef __attribute__((ext_vector_type(4))) u16 u16x4;
typedef __attribute__((ext_vector_type(8))) u16 u16x8;

__device__ __forceinline__ u16 f2bf(float f) {
  u32 u = __builtin_bit_cast(u32, f);
  return (u16)((u + 0x7fffu + ((u >> 16) & 1u)) >> 16);
}
__device__ __forceinline__ float bf2f(u16 h) {
  return __builtin_bit_cast(float, (u32)h << 16);
}

__device__ __forceinline__ void gload_lds16(const void* g, void* l) {
  __builtin_amdgcn_global_load_lds((const __attribute__((address_space(1))) u32*)g,
                                   (__attribute__((address_space(3))) u32*)l, 16, 0, 0);
}

// ---------------- merged weight f32 -> bf16 (one launch) ----------------
#define CN0 655360           // 1024*2560/4
#define CN1 262144           // 2048*512/4
#define CN2 5242880          // 8*1024*2560/4
#define CN3 2097152          // 8*2048*512/4
__global__ __launch_bounds__(256) void cvt4_kernel(
    const float* __restrict__ s0, u16* __restrict__ d0,
    const float* __restrict__ s1, u16* __restrict__ d1,
    const float* __restrict__ s2, u16* __restrict__ d2,
    const float* __restrict__ s3, u16* __restrict__ d3) {
  int i = blockIdx.x * 256 + threadIdx.x;
  const float* s; u16* d;
  if (i < CN0) { s = s0; d = d0; }
  else if (i < CN0 + CN1) { i -= CN0; s = s1; d = d1; }
  else if (i < CN0 + CN1 + CN2) { i -= CN0 + CN1; s = s2; d = d2; }
  else { i -= CN0 + CN1 + CN2; if (i >= CN3) return; s = s3; d = d3; }
  f32x4 v = ((const f32x4*)s)[i];
  u16x4 o = { f2bf(v.x), f2bf(v.y), f2bf(v.z), f2bf(v.w) };
  ((u16x4*)d)[i] = o;
}

// ---------------- fused pre-LN + router: one wave/token, rw via LDS --------
__global__ __launch_bounds__(256) void ln_router_kernel(
    const float* __restrict__ x, const float* __restrict__ gamma, const float* __restrict__ beta,
    const float* __restrict__ rw, const float* __restrict__ rb,
    u16* __restrict__ nx, int* __restrict__ tok_e, float* __restrict__ tok_w,
    int* __restrict__ count) {
  const int tid = threadIdx.x;
  const int t = blockIdx.x * 4 + (tid >> 6);
  const int lane = tid & 63;
  const f32x4* xrow = (const f32x4*)(x + (size_t)t * DIN);

  __shared__ float rwl[NEXP][256];   // 8 KB chunk of router weights

  f32x4 xv[10];
  float s = 0.f, s2 = 0.f;
#pragma unroll
  for (int c = 0; c < 10; ++c) {
    xv[c] = xrow[c * 64 + lane];
#pragma unroll
    for (int i = 0; i < 4; ++i) { s += xv[c][i]; s2 += xv[c][i] * xv[c][i]; }
  }
#pragma unroll
  for (int off = 32; off > 0; off >>= 1) {
    s += __shfl_xor(s, off);
    s2 += __shfl_xor(s2, off);
  }
  const float mean = s * (1.0f / DIN);
  const float var = s2 * (1.0f / DIN) - mean * mean;
  const float rstd = rsqrtf(var + 1e-6f);

  u16* nxrow = nx + (size_t)t * DIN;
#pragma unroll
  for (int c = 0; c < 10; ++c) {
    f32x4 g = ((const f32x4*)gamma)[c * 64 + lane];
    f32x4 b = ((const f32x4*)beta)[c * 64 + lane];
    xv[c] = (xv[c] - mean) * rstd * g + b;
    u16x4 p = { f2bf(xv[c].x), f2bf(xv[c].y), f2bf(xv[c].z), f2bf(xv[c].w) };
    ((u16x4*)nxrow)[c * 64 + lane] = p;
  }

  float lp[NEXP];
#pragma unroll
  for (int e = 0; e < NEXP; ++e) lp[e] = 0.f;
#pragma unroll
  for (int c = 0; c < 10; ++c) {
    __syncthreads();
#pragma unroll
    for (int e = 0; e < NEXP; ++e) rwl[e][tid] = rw[(size_t)e * DIN + c * 256 + tid];
    __syncthreads();
#pragma unroll
    for (int e = 0; e < NEXP; ++e) {
      f32x4 r = *(const f32x4*)&rwl[e][lane * 4];
      lp[e] += xv[c].x * r.x + xv[c].y * r.y + xv[c].z * r.z + xv[c].w * r.w;
    }
  }
#pragma unroll
  for (int e = 0; e < NEXP; ++e)
#pragma unroll
    for (int off = 32; off > 0; off >>= 1) lp[e] += __shfl_xor(lp[e], off);

  if (lane == 0) {
    float lg[NEXP];
#pragma unroll
    for (int e = 0; e < NEXP; ++e) lg[e] = lp[e] + rb[e];
    float mx = lg[0];
#pragma unroll
    for (int e = 1; e < NEXP; ++e) mx = fmaxf(mx, lg[e]);
    float p[NEXP], ps = 0.f;
#pragma unroll
    for (int e = 0; e < NEXP; ++e) { p[e] = expf(lg[e] - mx); ps += p[e]; }
    int i0 = 0;
#pragma unroll
    for (int e = 1; e < NEXP; ++e) if (p[e] > p[i0]) i0 = e;
    int i1 = (i0 == 0) ? 1 : 0;
#pragma unroll
    for (int e = 0; e < NEXP; ++e) if (e != i0 && p[e] > p[i1]) i1 = e;
    float w0 = p[i0] / ps, w1 = p[i1] / ps;
    const float inv = 1.0f / (w0 + w1 + 1e-20f);
    w0 *= inv; w1 *= inv;
    tok_e[2 * t] = i0; tok_e[2 * t + 1] = i1;
    tok_w[2 * t] = w0; tok_w[2 * t + 1] = w1;
    atomicAdd(&count[i0 * 32], 1);
    atomicAdd(&count[i1 * 32], 1);
  }
}

__global__ void prefix_kernel(const int* __restrict__ count, int* __restrict__ prefix) {
  if (threadIdx.x == 0) {
    int acc = 0;
    for (int e = 0; e < NEXP; ++e) { prefix[e] = acc; acc += count[e * 32]; }
  }
}

__global__ __launch_bounds__(256) void assign_kernel(
    const int* __restrict__ tok_e, const float* __restrict__ tok_w, const int* __restrict__ prefix,
    int* __restrict__ cursor, int* __restrict__ slot_token, float* __restrict__ slot_w,
    int* __restrict__ token_slot) {
  const int t = blockIdx.x * 256 + threadIdx.x;
  if (t >= T_TOK) return;
#pragma unroll
  for (int k = 0; k < 2; ++k) {
    const int e = tok_e[2 * t + k];
    const int pos = atomicAdd(&cursor[e * 32], 1);
    const int sl = prefix[e] + pos;
    slot_token[sl] = t;
    slot_w[sl] = tok_w[2 * t + k];
    token_slot[2 * t + k] = sl;
  }
}

// ---------------- FFN1 fused with SwiGLU (FROZEN from R10) ------------------
__global__ __launch_bounds__(256, 2) void gemm_ffn1(
    const u16* __restrict__ A0, const u16* __restrict__ Bsh, const u16* __restrict__ Bex,
    u16* __restrict__ ACT,
    const int* __restrict__ cnt32, const int* __restrict__ prefix,
    const int* __restrict__ slot_token) {
  constexpr int K = 2560;
  constexpr int NX = 8;            // 512 act cols / 64
  __shared__ u16 ldsA[128 * 64];
  __shared__ u16 ldsG[64 * 64];
  __shared__ u16 ldsV[64 * 64];

  int A_act = 0;
#pragma unroll
  for (int ee = 0; ee < 9; ++ee) {
    const int c = (ee == 8) ? MSH : cnt32[ee * 32];
    A_act += ((c + 127) >> 7) * NX;
  }
  const int bid = blockIdx.x;
  if (bid >= A_act) return;

  const int xcd = bid & 7, rank = bid >> 3;
  const int q = A_act >> 3, r = A_act & 7;
  const int tile = (xcd < r ? xcd * (q + 1) : r * (q + 1) + (xcd - r) * q) + rank;

  int e = 8, local = 0, m_valid = MSH, row_off = 0;
  {
    int bacc = 0, found = 0;
#pragma unroll
    for (int ee = 0; ee < 9; ++ee) {
      const int c = (ee == 8) ? MSH : cnt32[ee * 32];
      const int w = ((c + 127) >> 7) * NX;
      if (!found && tile < bacc + w) {
        found = 1; e = ee; local = tile - bacc; m_valid = c;
        row_off = (ee == 8) ? 0 : prefix[ee];
      }
      bacc += w;
    }
  }
  const int ty = local / NX;
  const int tx = local % NX;
  const int crow_base = (e == 8) ? SHBASE : row_off;
  const u16* Bb = (e == 8) ? Bsh : Bex + (size_t)e * 1024 * K;

  const int tid = threadIdx.x;
  const int lane = tid & 63;
  const int wid = tid >> 6;
  const int sk8 = ((lane & 7) ^ (lane >> 3)) * 8;   // pre-swizzled 16B slot

  const u16* aptr[4];
#pragma unroll
  for (int i = 0; i < 4; ++i) {
    const int rr = wid * 32 + i * 8 + (lane >> 3);
    int gr = ty * 128 + rr;
    gr = gr < m_valid ? gr : (m_valid - 1);
    const int ar = (e == 8) ? gr : slot_token[row_off + gr];
    aptr[i] = A0 + (size_t)ar * K;
  }
  const u16* gptr[2];
  const u16* vptr[2];
#pragma unroll
  for (int j = 0; j < 2; ++j) {
    const int rr = wid * 16 + j * 8 + (lane >> 3);
    gptr[j] = Bb + (size_t)(tx * 64 + rr) * K;
    vptr[j] = Bb + (size_t)(512 + tx * 64 + rr) * K;
  }

  const f32x4 zero = {0.f, 0.f, 0.f, 0.f};
  f32x4 accg[4][2], accv[4][2];
#pragma unroll
  for (int m = 0; m < 4; ++m)
#pragma unroll
    for (int n = 0; n < 2; ++n) { accg[m][n] = zero; accv[m][n] = zero; }

  const int wr = (wid >> 1) * 64;   // row half
  const int wc = (wid & 1) * 32;    // act-col half
  const int fr = lane & 15;
  const int fk = (lane >> 4) * 8;

  for (int k0 = 0; k0 < K; k0 += 64) {
#pragma unroll
    for (int i = 0; i < 4; ++i)
      gload_lds16(aptr[i] + k0 + sk8, &ldsA[(wid * 4 + i) * 512]);
#pragma unroll
    for (int j = 0; j < 2; ++j) {
      gload_lds16(gptr[j] + k0 + sk8, &ldsG[(wid * 2 + j) * 512]);
      gload_lds16(vptr[j] + k0 + sk8, &ldsV[(wid * 2 + j) * 512]);
    }
    __syncthreads();
#pragma unroll
    for (int kk = 0; kk < 2; ++kk) {
      short8 af[4], bg[2], bv[2];
      const int kbs = (kk * 32 + fk) ^ ((lane & 7) << 3);
#pragma unroll
      for (int m = 0; m < 4; ++m)
        af[m] = *(const short8*)&ldsA[(wr + m * 16 + fr) * 64 + kbs];
#pragma unroll
      for (int n = 0; n < 2; ++n) {
        bg[n] = *(const short8*)&ldsG[(wc + n * 16 + fr) * 64 + kbs];
        bv[n] = *(const short8*)&ldsV[(wc + n * 16 + fr) * 64 + kbs];
      }
#pragma unroll
      for (int m = 0; m < 4; ++m)
#pragma unroll
        for (int n = 0; n < 2; ++n) {
          accg[m][n] = __builtin_amdgcn_mfma_f32_16x16x32_bf16(af[m], bg[n], accg[m][n], 0, 0, 0);
          accv[m][n] = __builtin_amdgcn_mfma_f32_16x16x32_bf16(af[m], bv[n], accv[m][n], 0, 0, 0);
        }
    }
    __syncthreads();
  }

  const int ccol = tx * 64 + wc + (lane & 15);
#pragma unroll
  for (int m = 0; m < 4; ++m) {
#pragma unroll
    for (int i = 0; i < 4; ++i) {
      const int row = wr + m * 16 + (lane >> 4) * 4 + i;
      const int gr = ty * 128 + row;
      if (gr < m_valid) {
        u16* crow = ACT + (size_t)(crow_base + gr) * DH;
#pragma unroll
        for (int n = 0; n < 2; ++n) {
          const float g = accg[m][n][i];
          const float v = accv[m][n][i];
          const float sig = 1.0f / (1.0f + __expf(-g));
          crow[ccol + n * 16] = f2bf(g * sig * v);
        }
      }
    }
  }
}

// ---------------- FFN2 (REVERTED to R10-proven: BK=64, direct stores) -------
// R11 post-mortem: BK=128 + LDS-transpose epilogue cost ~27us (stores are
// fire-and-forget -> transpose was pure overhead; 16 staging pointers ->
// register pressure). This is the R10 version verbatim.
__global__ __launch_bounds__(256, 2) void gemm_ffn2(
    const u16* __restrict__ A0, const u16* __restrict__ Bsh, const u16* __restrict__ Bex,
    u16* __restrict__ C,
    const int* __restrict__ cnt32, const int* __restrict__ prefix,
    const float* __restrict__ slot_w) {
  constexpr int N = 2048;
  constexpr int K = 512;
  constexpr int NX = 16;
  __shared__ u16 ldsA[128 * 64];
  __shared__ u16 ldsB[128 * 64];

  int A_act = 0;
#pragma unroll
  for (int ee = 0; ee < 9; ++ee) {
    const int c = (ee == 8) ? MSH : cnt32[ee * 32];
    A_act += ((c + 127) >> 7) * NX;
  }
  const int bid = blockIdx.x;
  if (bid >= A_act) return;

  const int xcd = bid & 7, rank = bid >> 3;
  const int q = A_act >> 3, r = A_act & 7;
  const int tile = (xcd < r ? xcd * (q + 1) : r * (q + 1) + (xcd - r) * q) + rank;

  int e = 8, local = 0, m_valid = MSH, row_off = 0;
  {
    int bacc = 0, found = 0;
#pragma unroll
    for (int ee = 0; ee < 9; ++ee) {
      const int c = (ee == 8) ? MSH : cnt32[ee * 32];
      const int w = ((c + 127) >> 7) * NX;
      if (!found && tile < bacc + w) {
        found = 1; e = ee; local = tile - bacc; m_valid = c;
        row_off = (ee == 8) ? 0 : prefix[ee];
      }
      bacc += w;
    }
  }
  const int ty = local / NX;
  const int tx = local % NX;
  const int crow_base = (e == 8) ? SHBASE : row_off;
  const u16* Bb = (e == 8) ? Bsh : Bex + (size_t)e * N * K;

  const int tid = threadIdx.x;
  const int lane = tid & 63;
  const int wid = tid >> 6;
  const int sk8 = ((lane & 7) ^ (lane >> 3)) * 8;

  const u16* aptr[4];
  const u16* bptr[4];
#pragma unroll
  for (int i = 0; i < 4; ++i) {
    const int rr = wid * 32 + i * 8 + (lane >> 3);
    int gr = ty * 128 + rr;
    gr = gr < m_valid ? gr : (m_valid - 1);
    aptr[i] = A0 + (size_t)(crow_base + gr) * K;
    bptr[i] = Bb + (size_t)(tx * 128 + rr) * K;
  }

  const f32x4 zero = {0.f, 0.f, 0.f, 0.f};
  f32x4 acc[4][4];
#pragma unroll
  for (int m = 0; m < 4; ++m)
#pragma unroll
    for (int n = 0; n < 4; ++n) acc[m][n] = zero;

  const int wr = (wid >> 1) * 64;
  const int wc = (wid & 1) * 64;
  const int fr = lane & 15;
  const int fk = (lane >> 4) * 8;

  for (int k0 = 0; k0 < K; k0 += 64) {
#pragma unroll
    for (int i = 0; i < 4; ++i) {
      gload_lds16(aptr[i] + k0 + sk8, &ldsA[(wid * 4 + i) * 512]);
      gload_lds16(bptr[i] + k0 + sk8, &ldsB[(wid * 4 + i) * 512]);
    }
    __syncthreads();
#pragma unroll
    for (int kk = 0; kk < 2; ++kk) {
      short8 af[4], bfm[4];
      const int kbs = (kk * 32 + fk) ^ ((lane & 7) << 3);
#pragma unroll
      for (int m = 0; m < 4; ++m)
        af[m] = *(const short8*)&ldsA[(wr + m * 16 + fr) * 64 + kbs];
#pragma unroll
      for (int n = 0; n < 4; ++n)
        bfm[n] = *(const short8*)&ldsB[(wc + n * 16 + fr) * 64 + kbs];
#pragma unroll
      for (int m = 0; m < 4; ++m)
#pragma unroll
        for (int n = 0; n < 4; ++n)
          acc[m][n] = __builtin_amdgcn_mfma_f32_16x16x32_bf16(af[m], bfm[n], acc[m][n], 0, 0, 0);
    }
    __syncthreads();
  }

  const int ccol = wc + (lane & 15);
#pragma unroll
  for (int m = 0; m < 4; ++m) {
#pragma unroll
    for (int i = 0; i < 4; ++i) {
      const int row = wr + m * 16 + (lane >> 4) * 4 + i;
      const int gr = ty * 128 + row;
      if (gr < m_valid) {
        const float wscale = (e == 8) ? 1.0f : slot_w[row_off + gr];
        u16* crow = C + (size_t)(crow_base + gr) * N + tx * 128;
#pragma unroll
        for (int n = 0; n < 4; ++n) crow[ccol + n * 16] = f2bf(acc[m][n][i] * wscale);
      }
    }
  }
}

// ---------------- final LN: one wave per token ------------------------------
__global__ __launch_bounds__(256) void final_ln_kernel(
    const u16* __restrict__ O16, const int* __restrict__ token_slot,
    const float* __restrict__ gamma, const float* __restrict__ beta, float* __restrict__ out) {
  const int t = blockIdx.x * 4 + (threadIdx.x >> 6);
  const int lane = threadIdx.x & 63;
  const int s0 = token_slot[2 * t], s1 = token_slot[2 * t + 1];
  const u16* rsh = O16 + (size_t)(SHBASE + t) * DOUT;
  const u16* r0 = O16 + (size_t)s0 * DOUT;
  const u16* r1 = O16 + (size_t)s1 * DOUT;

  float v[32];
  float s = 0.f, s2 = 0.f;
#pragma unroll
  for (int c = 0; c < 4; ++c) {
    const int col = c * 512 + lane * 8;
    u16x8 a8 = *(const u16x8*)&rsh[col];
    u16x8 b8 = *(const u16x8*)&r0[col];
    u16x8 c8 = *(const u16x8*)&r1[col];
#pragma unroll
    for (int i = 0; i < 8; ++i) {
      const float x = bf2f(a8[i]) + bf2f(b8[i]) + bf2f(c8[i]);
      v[c * 8 + i] = x;
      s += x;
      s2 += x * x;
    }
  }
#pragma unroll
  for (int off = 32; off > 0; off >>= 1) {
    s += __shfl_xor(s, off);
    s2 += __shfl_xor(s2, off);
  }
  const float mean = s * (1.0f / DOUT);
  const float var = s2 * (1.0f / DOUT) - mean * mean;
  const float rstd = rsqrtf(var + 1e-6f);

  float* orow = out + (size_t)t * DOUT;
#pragma unroll
  for (int c = 0; c < 4; ++c) {
    const int col = c * 512 + lane * 8;
    f32x4 g0 = ((const f32x4*)gamma)[col >> 2], g1 = ((const f32x4*)gamma)[(col >> 2) + 1];
    f32x4 b0 = ((const f32x4*)beta)[col >> 2],  b1 = ((const f32x4*)beta)[(col >> 2) + 1];
    f32x4 o0, o1;
#pragma unroll
    for (int i = 0; i < 4; ++i) {
      o0[i] = (v[c * 8 + i] - mean) * rstd * g0[i] + b0[i];
      o1[i] = (v[c * 8 + 4 + i] - mean) * rstd * g1[i] + b1[i];
    }
    *(f32x4*)&orow[col] = o0;
    *(f32x4*)&orow[col + 4] = o1;
  }
}

extern "C" void kernel_launch(void* const* d_in, const int* in_sizes, int n_in,
                              void* d_out, int out_size, void* d_ws, size_t ws_size,
                              hipStream_t stream) {
  (void)in_sizes; (void)n_in; (void)out_size; (void)ws_size;
  const float* x = (const float*)d_in[0];
  const float* ln_pre_g = (const float*)d_in[1];
  const float* ln_pre_b = (const float*)d_in[2];
  const float* router_w = (const float*)d_in[3];
  const float* router_b = (const float*)d_in[4];
  const float* shared_w12 = (const float*)d_in[5];
  const float* shared_w3 = (const float*)d_in[6];
  const float* experts_w12 = (const float*)d_in[7];
  const float* experts_w3 = (const float*)d_in[8];
  const float* ln_post_g = (const float*)d_in[9];
  const float* ln_post_b = (const float*)d_in[10];
  float* out = (float*)d_out;

  size_t off = 0;
  char* ws = (char*)d_ws;
  auto take = [&](size_t bytes) -> void* {
    void* p = ws + off;
    off += (bytes + 255) & ~(size_t)255;
    return p;
  };
  u16* w12s = (u16*)take((size_t)1024 * 2560 * 2);
  u16* w3s  = (u16*)take((size_t)2048 * 512 * 2);
  u16* ew12 = (u16*)take((size_t)NEXP * 1024 * 2560 * 2);
  u16* ew3  = (u16*)take((size_t)NEXP * 2048 * 512 * 2);
  u16* nx   = (u16*)take((size_t)T_TOK * DIN * 2);
  u16* act  = (u16*)take((size_t)36000 * DH * 2);
  u16* O16  = (u16*)take((size_t)36000 * DOUT * 2);
  int* tok_e = (int*)take(NSLOT * 4);
  float* tok_w = (float*)take(NSLOT * 4);
  int* slot_token = (int*)take(NSLOT * 4);
  float* slot_w = (float*)take(NSLOT * 4);
  int* token_slot = (int*)take(NSLOT * 4);
  int* cnt = (int*)take(3 * 8 * 32 * 4);   // count[8*32] | cursor[8*32] | prefix[8]
  int* cursor = cnt + 8 * 32;
  int* prefix = cnt + 2 * 8 * 32;

  hipMemsetAsync(cnt, 0, 3 * 8 * 32 * 4, stream);

  cvt4_kernel<<<(CN0 + CN1 + CN2 + CN3) / 256, 256, 0, stream>>>(
      shared_w12, w12s, shared_w3, w3s, experts_w12, ew12, experts_w3, ew3);

  ln_router_kernel<<<T_TOK / 4, 256, 0, stream>>>(x, ln_pre_g, ln_pre_b, router_w, router_b,
                                                  nx, tok_e, tok_w, cnt);
  prefix_kernel<<<1, 64, 0, stream>>>(cnt, prefix);
  assign_kernel<<<(T_TOK + 255) / 256, 256, 0, stream>>>(tok_e, tok_w, prefix, cursor,
                                                         slot_token, slot_w, token_slot);

  // y-tiles (128-row): experts <= 195, shared 94 -> 289 max
  gemm_ffn1<<<289 * 8, 256, 0, stream>>>(nx, w12s, ew12, act, cnt, prefix, slot_token);
  gemm_ffn2<<<289 * 16, 256, 0, stream>>>(act, w3s, ew3, O16, cnt, prefix, slot_w);

  final_ln_kernel<<<T_TOK / 4, 256, 0, stream>>>(O16, token_slot, ln_post_g, ln_post_b, out);
}